// Round 7
// baseline (1454.293 us; speedup 1.0000x reference)
//
#include <hip/hip_runtime.h>
#include <hip/hip_fp16.h>

#define S_LEN 512
#define BATCH 32
#define CHUNK 16

typedef _Float16 hv2   __attribute__((ext_vector_type(2)));
typedef _Float16 hv4   __attribute__((ext_vector_type(4)));
typedef _Float16 half8 __attribute__((ext_vector_type(8)));
typedef float    f32x4 __attribute__((ext_vector_type(4)));

__device__ __forceinline__ float fast_tanh(float x) {
    float e = __expf(2.f * x);
    return 1.f - 2.f / (e + 1.f);
}

// LDS-only step barrier (no vmcnt drain) — global traffic stays in flight.
__device__ __forceinline__ void lds_barrier() {
    __asm__ volatile("s_waitcnt lgkmcnt(0)\n\ts_barrier" ::: "memory");
}
__device__ __forceinline__ void vm_drain() {
    __asm__ volatile("s_waitcnt vmcnt(0)" ::: "memory");
}

// ---------------------------------------------------------------------------
// Prep: padded f16 conversions (relu fused for emb). Zeroes flags.
// ---------------------------------------------------------------------------
#define E8   1280000   // 32000*320/8
#define W18  64000     // 320*1600/8
#define W28  12800     // 320*320/8
#define FF8  5120      // 128*320/8
#define PREP_TOTAL8 (E8 + W18 + W28 + FF8 + FF8)

__global__ __launch_bounds__(256) void k_prep(
    const float* __restrict__ emb,  const float* __restrict__ Wih1,
    const float* __restrict__ Wih2, const float* __restrict__ fc1w,
    const float* __restrict__ fc2w,
    _Float16* __restrict__ embf, _Float16* __restrict__ Wf1,
    _Float16* __restrict__ Wf2,  _Float16* __restrict__ F1,
    _Float16* __restrict__ F2,   unsigned int* __restrict__ flags)
{
    int gid = blockIdx.x * 256 + threadIdx.x;
    if (gid < 64) flags[gid] = 0u;
    if (gid >= PREP_TOTAL8) return;

    half8 v;
    _Float16* dst;

    if (gid < E8) {
        int row = gid / 40, c8 = (gid - row * 40) * 8;
        #pragma unroll
        for (int j = 0; j < 8; ++j) {
            int c = c8 + j;
            float f = (c < 300) ? emb[(size_t)row * 300 + c] : 0.f;
            v[j] = (_Float16)(f > 0.f ? f : 0.f);
        }
        dst = embf + (size_t)gid * 8;
    } else if (gid < E8 + W18) {
        int i = gid - E8;
        int row = i / 200, c8 = (i - row * 200) * 8;
        #pragma unroll
        for (int j = 0; j < 8; ++j) {
            int c = c8 + j, w = c / 320, cc = c - w * 320;
            float f = (row < 300 && cc < 300) ? Wih1[(size_t)row * 1500 + w * 300 + cc] : 0.f;
            v[j] = (_Float16)f;
        }
        dst = Wf1 + (size_t)i * 8;
    } else if (gid < E8 + W18 + W28) {
        int i = gid - E8 - W18;
        int row = i / 40, c8 = (i - row * 40) * 8;
        #pragma unroll
        for (int j = 0; j < 8; ++j) {
            int c = c8 + j;
            float f = (row < 300 && c < 300) ? Wih2[(size_t)row * 300 + c] : 0.f;
            v[j] = (_Float16)f;
        }
        dst = Wf2 + (size_t)i * 8;
    } else if (gid < E8 + W18 + W28 + FF8) {
        int i = gid - E8 - W18 - W28;
        int row = i / 40, c8 = (i - row * 40) * 8;
        #pragma unroll
        for (int j = 0; j < 8; ++j) {
            int c = c8 + j;
            v[j] = (_Float16)((c < 300) ? fc1w[(size_t)row * 300 + c] : 0.f);
        }
        dst = F1 + (size_t)i * 8;
    } else {
        int i = gid - E8 - W18 - W28 - FF8;
        int row = i / 40, c8 = (i - row * 40) * 8;
        #pragma unroll
        for (int j = 0; j < 8; ++j) {
            int c = c8 + j;
            v[j] = (_Float16)((c < 300) ? fc2w[(size_t)row * 300 + c] : 0.f);
        }
        dst = F2 + (size_t)i * 8;
    }
    *(half8*)dst = v;
}

// ---------------------------------------------------------------------------
// GEMM1 (MFMA, fused embedding gather). grid (128,2), block 256.
// Epilogue now writes U transposed f16: U1T[t][n(320)][b(32)].
// ---------------------------------------------------------------------------
__global__ __launch_bounds__(256) void k_gemm1_mfma(
    const int* __restrict__ x, const _Float16* __restrict__ embf,
    const _Float16* __restrict__ Wf1, const float* __restrict__ b1,
    const float* __restrict__ b2, _Float16* __restrict__ U)
{
    const int wid  = threadIdx.x >> 6;
    const int lane = threadIdx.x & 63;
    const int m    = lane & 15;
    const int q    = lane >> 4;
    const int r0   = blockIdx.x * 128 + wid * 32;
    const int n0   = blockIdx.y * 160;

    f32x4 acc[2][10];
    #pragma unroll
    for (int i = 0; i < 2; ++i)
        #pragma unroll
        for (int j = 0; j < 10; ++j)
            acc[i][j] = (f32x4){0.f, 0.f, 0.f, 0.f};

    const int rA = r0 + m, rB = r0 + 16 + m;
    const int xbA = ((rA & 31) * S_LEN + (rA >> 5)) * 5;
    const int xbB = ((rB & 31) * S_LEN + (rB >> 5)) * 5;

    for (int w = 0; w < 5; ++w) {
        const int idxA = x[xbA + w];
        const int idxB = x[xbB + w];
        const _Float16* ea = embf + (size_t)idxA * 320;
        const _Float16* eb = embf + (size_t)idxB * 320;
        const _Float16* wb = Wf1 + (size_t)w * 320;
        #pragma unroll
        for (int c = 0; c < 10; ++c) {
            const int k = c * 32 + q * 8;
            half8 a0 = *(const half8*)(ea + k);
            half8 a1 = *(const half8*)(eb + k);
            #pragma unroll
            for (int nt = 0; nt < 10; ++nt) {
                half8 bf = *(const half8*)(wb + (size_t)(n0 + nt * 16 + m) * 1600 + k);
                acc[0][nt] = __builtin_amdgcn_mfma_f32_16x16x32_f16(a0, bf, acc[0][nt], 0, 0, 0);
                acc[1][nt] = __builtin_amdgcn_mfma_f32_16x16x32_f16(a1, bf, acc[1][nt], 0, 0, 0);
            }
        }
    }

    #pragma unroll
    for (int nt = 0; nt < 10; ++nt) {
        const int n = n0 + nt * 16 + m;
        const float bias = (n < 300) ? (b1[n] + b2[n]) : 0.f;
        #pragma unroll
        for (int mt = 0; mt < 2; ++mt) {
            #pragma unroll
            for (int reg = 0; reg < 4; ++reg) {
                const int r = r0 + mt * 16 + q * 4 + reg;     // r = t*32 + b
                U[((size_t)(r >> 5) * 320 + n) * 32 + (r & 31)] =
                    (_Float16)(acc[mt][nt][reg] + bias);
            }
        }
    }
}

// ---------------------------------------------------------------------------
// FC (MFMA): per-wave 32x128. grid (128, 2): y = layer.
// ---------------------------------------------------------------------------
__global__ __launch_bounds__(256) void k_fc_mfma(
    const _Float16* __restrict__ H1, const _Float16* __restrict__ H2,
    const _Float16* __restrict__ F1, const _Float16* __restrict__ F2,
    const float* __restrict__ fb1, const float* __restrict__ fb2,
    float* __restrict__ out1, float* __restrict__ out2)
{
    const int layer = blockIdx.y;
    const _Float16* H = layer ? H2 : H1;
    const _Float16* F = layer ? F2 : F1;
    const float* bias = layer ? fb2 : fb1;
    float* out        = layer ? out2 : out1;

    const int wid  = threadIdx.x >> 6;
    const int lane = threadIdx.x & 63;
    const int m    = lane & 15;
    const int q    = lane >> 4;
    const int r0   = blockIdx.x * 128 + wid * 32;

    f32x4 acc[2][8];
    #pragma unroll
    for (int i = 0; i < 2; ++i)
        #pragma unroll
        for (int j = 0; j < 8; ++j)
            acc[i][j] = (f32x4){0.f, 0.f, 0.f, 0.f};

    const _Float16* ha = H + (size_t)(r0 + m) * 320;
    const _Float16* hb = H + (size_t)(r0 + 16 + m) * 320;

    #pragma unroll
    for (int c = 0; c < 10; ++c) {
        const int k = c * 32 + q * 8;
        half8 a0 = *(const half8*)(ha + k);
        half8 a1 = *(const half8*)(hb + k);
        #pragma unroll
        for (int nt = 0; nt < 8; ++nt) {
            half8 bf = *(const half8*)(F + (size_t)(nt * 16 + m) * 320 + k);
            acc[0][nt] = __builtin_amdgcn_mfma_f32_16x16x32_f16(a0, bf, acc[0][nt], 0, 0, 0);
            acc[1][nt] = __builtin_amdgcn_mfma_f32_16x16x32_f16(a1, bf, acc[1][nt], 0, 0, 0);
        }
    }

    #pragma unroll
    for (int nt = 0; nt < 8; ++nt) {
        const int n = nt * 16 + m;
        const float bv = bias[n];
        #pragma unroll
        for (int mt = 0; mt < 2; ++mt) {
            #pragma unroll
            for (int reg = 0; reg < 4; ++reg) {
                const int r = r0 + mt * 16 + q * 4 + reg;
                const int oidx = ((r & 31) * S_LEN + (r >> 5)) * 128 + n;
                out[oidx] = acc[mt][nt][reg] + bv;
            }
        }
    }
}

// ---------------------------------------------------------------------------
// MFMA recurrence pipeline. Grid 8 x 512:
//  blk 0,1: producer (layer1, 16 chains each)   release pf[g]
//  blk 2-5: helper   (Wih2·h1 chunk GEMM)       wait pf, release hf[idx]
//  blk 6,7: consumer (layer2, 16 chains each)   wait hf pair
// rec step: D[n][chain] = Whh·h via 16x16x32 MFMA; W A-frags register-
// resident; h double-buffered in LDS in B-frag order (group G=4kt+q',
// [chain][j], stride 136 f16); ONE lgkm barrier/step. U prefetched from
// global f16 [t][n][b]; H written as scattered b16 (drained per chunk).
// LDS: 2 x 40 x 136 f16 = 21,760 B (dynamic).
// ---------------------------------------------------------------------------
#define GSTR   136
#define BUFSTR (40 * GSTR)
#define LDS_BYTES (2 * BUFSTR * 2)

__device__ __forceinline__ void load_u12(_Float16* u, const _Float16* __restrict__ Ut,
                                         int t, int tbase, int ntile, int lm, int q, int b0) {
    #pragma unroll
    for (int ti = 0; ti < 3; ++ti)
        #pragma unroll
        for (int r = 0; r < 4; ++r) {
            if (ti < ntile) {
                const int n = (tbase + ti) * 16 + q * 4 + r;
                u[ti * 4 + r] = Ut[((size_t)t * 320 + n) * 32 + b0 + lm];
            } else u[ti * 4 + r] = (_Float16)0.f;
        }
}

__device__ __forceinline__ void rec_core(
    const _Float16* __restrict__ Ut, const float* __restrict__ Whh,
    _Float16* __restrict__ Hf, int b0,
    unsigned int* relFlag,
    const unsigned int* waitA, const unsigned int* waitB,
    char* smem)
{
    const int tid  = threadIdx.x;
    const int lane = tid & 63;
    const int w    = tid >> 6;          // 0..7
    const int lm   = lane & 15;
    const int q    = lane >> 4;
    int ntile, tbase;
    if (w < 4) { ntile = 3; tbase = 3 * w; } else { ntile = 2; tbase = 12 + 2 * (w - 4); }

    _Float16* hB = (_Float16*)smem;

    for (int i = tid; i < 2 * BUFSTR; i += 512) hB[i] = (_Float16)0.f;

    // W A-frags: wa[ti][kt] lane holds W[n=(tbase+ti)*16+lm][k=kt*32+q*8+j]
    half8 wa[3][10];
    for (int ti = 0; ti < 3; ++ti)
        for (int kt = 0; kt < 10; ++kt) {
            half8 v;
            const int n = (tbase + ti) * 16 + lm;
            #pragma unroll
            for (int j = 0; j < 8; ++j) {
                const int k = kt * 32 + q * 8 + j;
                float f = (ti < ntile && n < 300 && k < 300) ? Whh[(size_t)n * 300 + k] : 0.f;
                v[j] = (_Float16)f;
            }
            wa[ti][kt] = v;
        }
    __syncthreads();

    _Float16 upf[12], upn[12];

    for (int c = 0; c < 32; ++c) {
        const int t0 = c * CHUNK;
        if (waitA) {
            if (tid == 0) {
                while (__hip_atomic_load(waitA, __ATOMIC_ACQUIRE, __HIP_MEMORY_SCOPE_AGENT) < (unsigned)(t0 + CHUNK) ||
                       __hip_atomic_load(waitB, __ATOMIC_ACQUIRE, __HIP_MEMORY_SCOPE_AGENT) < (unsigned)(t0 + CHUNK))
                    __builtin_amdgcn_s_sleep(2);
            }
            __syncthreads();
        }
        load_u12(upf, Ut, t0, tbase, ntile, lm, q, b0);

        for (int s = 0; s < CHUNK; ++s) {
            const int t = t0 + s;
            const _Float16* rb = hB + ((t & 1) ^ 1) * BUFSTR;   // h_{t-1}
            f32x4 a0 = {0.f,0.f,0.f,0.f}, a1 = {0.f,0.f,0.f,0.f}, a2 = {0.f,0.f,0.f,0.f};
            #pragma unroll
            for (int kt = 0; kt < 10; ++kt) {
                half8 hb = *(const half8*)(rb + (4 * kt + q) * GSTR + lm * 8);
                a0 = __builtin_amdgcn_mfma_f32_16x16x32_f16(wa[0][kt], hb, a0, 0, 0, 0);
                a1 = __builtin_amdgcn_mfma_f32_16x16x32_f16(wa[1][kt], hb, a1, 0, 0, 0);
                if (ntile > 2)
                    a2 = __builtin_amdgcn_mfma_f32_16x16x32_f16(wa[2][kt], hb, a2, 0, 0, 0);
            }
            if (s < CHUNK - 1) load_u12(upn, Ut, t + 1, tbase, ntile, lm, q, b0);

            _Float16* wbuf = hB + (t & 1) * BUFSTR;             // h_t
            #pragma unroll
            for (int ti = 0; ti < 3; ++ti) {
                if (ti < ntile) {
                    const f32x4 aa = (ti == 0) ? a0 : ((ti == 1) ? a1 : a2);
                    _Float16 h0 = (_Float16)fast_tanh(aa[0] + (float)upf[ti*4+0]);
                    _Float16 h1 = (_Float16)fast_tanh(aa[1] + (float)upf[ti*4+1]);
                    _Float16 h2 = (_Float16)fast_tanh(aa[2] + (float)upf[ti*4+2]);
                    _Float16 h3 = (_Float16)fast_tanh(aa[3] + (float)upf[ti*4+3]);
                    const int T = tbase + ti;
                    const int G = 4 * (T >> 1) + ((2 * T + (q >> 1)) & 3);
                    hv4 pk; pk[0] = h0; pk[1] = h1; pk[2] = h2; pk[3] = h3;
                    *(hv4*)(wbuf + G * GSTR + lm * 8 + 4 * (q & 1)) = pk;
                    const int nb = T * 16 + q * 4;
                    _Float16* hp = &Hf[((size_t)(t * 32 + b0 + lm)) * 320 + nb];
                    hp[0] = h0; hp[1] = h1; hp[2] = h2; hp[3] = h3;
                }
            }
            lds_barrier();
            #pragma unroll
            for (int i2 = 0; i2 < 12; ++i2) upf[i2] = upn[i2];
        }
        if (relFlag) {
            vm_drain();
            __syncthreads();
            if (tid == 0)
                __hip_atomic_store(relFlag, (unsigned)(t0 + CHUNK),
                                   __ATOMIC_RELEASE, __HIP_MEMORY_SCOPE_AGENT);
        }
    }
}

__global__ __launch_bounds__(512, 2) void k_rec_pipe(
    const _Float16* __restrict__ U1T, const float* __restrict__ Whh1,
    const float* __restrict__ Whh2, const _Float16* __restrict__ Wf2,
    const float* __restrict__ bih2, const float* __restrict__ bhh2,
    _Float16* __restrict__ H1f, _Float16* __restrict__ H2f,
    _Float16* __restrict__ U2T, unsigned int* __restrict__ flags)
{
    extern __shared__ char smem[];
    const int bx = blockIdx.x;

    if (bx < 2) {
        rec_core(U1T, Whh1, H1f, bx * 16, &flags[bx], nullptr, nullptr, smem);
    } else if (bx < 6) {
        // ---------------- helper: U2T[t][n][b] = bias2[n] + Wih2 . h1[t][b] ----
        const int idx = bx - 2;             // 0..3
        const int g   = idx >> 1;
        const int hh  = idx & 1;            // m half (10 m-tiles each)
        const int b0  = g * 16;
        const int tid = threadIdx.x;
        const int lane = tid & 63;
        const int w   = tid >> 6;
        const int lm  = lane & 15;
        const int q   = lane >> 4;
        const int ms  = w >> 1;             // 0..3
        const int th  = w & 1;              // t-half
        const int mtb  = 10 * hh + ((5 * ms + 1) >> 1);   // {0,3,5,8}+10hh
        const int mcnt = 3 - (ms & 1);                    // {3,2,3,2}

        half8 af[3][10];
        float bs[12];
        for (int ti = 0; ti < 3; ++ti) {
            const int nrow = (mtb + ti) * 16 + lm;
            for (int kt = 0; kt < 10; ++kt) {
                if (ti < mcnt)
                    af[ti][kt] = *(const half8*)&Wf2[(size_t)nrow * 320 + kt * 32 + q * 8];
                else {
                    half8 z;
                    #pragma unroll
                    for (int j = 0; j < 8; ++j) z[j] = (_Float16)0.f;
                    af[ti][kt] = z;
                }
            }
            #pragma unroll
            for (int r = 0; r < 4; ++r) {
                const int n = (mtb + ti) * 16 + q * 4 + r;
                bs[ti * 4 + r] = (ti < mcnt && n < 300) ? (bih2[n] + bhh2[n]) : 0.f;
            }
        }

        for (int c = 0; c < 32; ++c) {
            const int t0 = c * CHUNK;
            if (tid == 0) {
                while (__hip_atomic_load(&flags[g], __ATOMIC_ACQUIRE,
                                         __HIP_MEMORY_SCOPE_AGENT) < (unsigned)(t0 + CHUNK))
                    __builtin_amdgcn_s_sleep(2);
            }
            __syncthreads();
            for (int tt = 0; tt < 8; ++tt) {
                const int t = t0 + th * 8 + tt;
                f32x4 a0 = {0.f,0.f,0.f,0.f}, a1 = {0.f,0.f,0.f,0.f}, a2 = {0.f,0.f,0.f,0.f};
                #pragma unroll
                for (int kt = 0; kt < 10; ++kt) {
                    half8 hb = *(const half8*)&H1f[((size_t)(t * 32 + b0 + lm)) * 320 + kt * 32 + q * 8];
                    a0 = __builtin_amdgcn_mfma_f32_16x16x32_f16(af[0][kt], hb, a0, 0, 0, 0);
                    a1 = __builtin_amdgcn_mfma_f32_16x16x32_f16(af[1][kt], hb, a1, 0, 0, 0);
                    if (mcnt > 2)
                        a2 = __builtin_amdgcn_mfma_f32_16x16x32_f16(af[2][kt], hb, a2, 0, 0, 0);
                }
                #pragma unroll
                for (int ti = 0; ti < 3; ++ti) {
                    if (ti < mcnt) {
                        const f32x4 aa = (ti == 0) ? a0 : ((ti == 1) ? a1 : a2);
                        #pragma unroll
                        for (int r = 0; r < 4; ++r) {
                            const int n = (mtb + ti) * 16 + q * 4 + r;
                            U2T[((size_t)t * 320 + n) * 32 + b0 + lm] =
                                (_Float16)(aa[r] + bs[ti * 4 + r]);
                        }
                    }
                }
            }
            vm_drain();
            __syncthreads();
            if (tid == 0)
                __hip_atomic_store(&flags[2 + idx], (unsigned)(t0 + CHUNK),
                                   __ATOMIC_RELEASE, __HIP_MEMORY_SCOPE_AGENT);
        }
    } else {
        const int g = bx - 6;
        rec_core(U2T, Whh2, H2f, g * 16, nullptr,
                 &flags[2 + 2 * g], &flags[2 + 2 * g + 1], smem);
    }
}

extern "C" void kernel_launch(void* const* d_in, const int* in_sizes, int n_in,
                              void* d_out, int out_size, void* d_ws, size_t ws_size,
                              hipStream_t stream) {
    const int*   x     = (const int*)d_in[0];
    const float* emb   = (const float*)d_in[1];
    const float* Wih1  = (const float*)d_in[2];
    const float* Whh1  = (const float*)d_in[3];
    const float* bih1  = (const float*)d_in[4];
    const float* bhh1  = (const float*)d_in[5];
    const float* Wih2  = (const float*)d_in[6];
    const float* Whh2  = (const float*)d_in[7];
    const float* bih2  = (const float*)d_in[8];
    const float* bhh2  = (const float*)d_in[9];
    const float* fc1w  = (const float*)d_in[10];
    const float* fc1b  = (const float*)d_in[11];
    const float* fc2w  = (const float*)d_in[12];
    const float* fc2b  = (const float*)d_in[13];

    float* out1 = (float*)d_out;
    float* out2 = out1 + (size_t)16384 * 128;

    char* w = (char*)d_ws;
    _Float16*     U1T   = (_Float16*)(w + 0);            // 10,485,760
    _Float16*     H1f   = (_Float16*)(w + 10485760);     // 10,485,760
    _Float16*     Wf2   = (_Float16*)(w + 20971520);     //    204,800
    _Float16*     F1    = (_Float16*)(w + 21176320);     //     81,920
    _Float16*     F2    = (_Float16*)(w + 21258240);     //     81,920
    unsigned int* flags = (unsigned int*)(w + 21340160); //        256
    _Float16*     EMBF  = (_Float16*)(w + 21340416);     // 20,480,000
    _Float16*     Wf1   = (_Float16*)(w + 41820416);     //  1,024,000  (end 42,844,416)
    // After gemm1, EMBF+Wf1 are dead -> reuse for H2f and U2T:
    _Float16*     H2f   = EMBF;                          // 10,485,760
    _Float16*     U2T   = (_Float16*)((char*)EMBF + 10485760); // 10,485,760 (spills into Wf1 region)

    const int prep_blocks = (PREP_TOTAL8 + 255) / 256;
    k_prep<<<prep_blocks, 256, 0, stream>>>(emb, Wih1, Wih2, fc1w, fc2w,
                                            EMBF, Wf1, Wf2, F1, F2, flags);

    dim3 g(128, 2);
    k_gemm1_mfma<<<g, 256, 0, stream>>>(x, EMBF, Wf1, bih1, bhh1, U1T);
    k_rec_pipe<<<8, 512, LDS_BYTES, stream>>>(U1T, Whh1, Whh2, Wf2, bih2, bhh2,
                                              H1f, H2f, U2T, flags);
    k_fc_mfma<<<g, 256, 0, stream>>>(H1f, H2f, F1, F2, fc1b, fc2b, out1, out2);
}

// Round 9
// 1048.853 us; speedup vs baseline: 1.3866x; 1.3866x over previous
//
#include <hip/hip_runtime.h>
#include <hip/hip_fp16.h>

#define S_LEN 512
#define BATCH 32
#define CHUNK 16

typedef _Float16 hv2   __attribute__((ext_vector_type(2)));
typedef _Float16 hv4   __attribute__((ext_vector_type(4)));
typedef _Float16 half8 __attribute__((ext_vector_type(8)));
typedef float    f32x4 __attribute__((ext_vector_type(4)));

__device__ __forceinline__ float fast_tanh(float x) {
    float e = __expf(2.f * x);
    return 1.f - 2.f / (e + 1.f);
}

// LDS-only step barrier (no vmcnt drain) — global traffic stays in flight.
__device__ __forceinline__ void lds_barrier() {
    __asm__ volatile("s_waitcnt lgkmcnt(0)\n\ts_barrier" ::: "memory");
}
__device__ __forceinline__ void vm_drain() {
    __asm__ volatile("s_waitcnt vmcnt(0)" ::: "memory");
}

// Fragment layout used for U1T/U2T/H1f/H2f:  [t][G=n>>3 (40)][b (32)][j=n&7 (8)]
// t-slice = 40*32*8 = 10240 f16 elements.
#define TSL 10240

// ---------------------------------------------------------------------------
// Prep: padded f16 conversions (relu fused for emb). Zeroes flags.
// ---------------------------------------------------------------------------
#define E8   1280000   // 32000*320/8
#define W18  64000     // 320*1600/8
#define W28  12800     // 320*320/8
#define FF8  5120      // 128*320/8
#define PREP_TOTAL8 (E8 + W18 + W28 + FF8 + FF8)

__global__ __launch_bounds__(256) void k_prep(
    const float* __restrict__ emb,  const float* __restrict__ Wih1,
    const float* __restrict__ Wih2, const float* __restrict__ fc1w,
    const float* __restrict__ fc2w,
    _Float16* __restrict__ embf, _Float16* __restrict__ Wf1,
    _Float16* __restrict__ Wf2,  _Float16* __restrict__ F1,
    _Float16* __restrict__ F2,   unsigned int* __restrict__ flags)
{
    int gid = blockIdx.x * 256 + threadIdx.x;
    if (gid < 64) flags[gid] = 0u;
    if (gid >= PREP_TOTAL8) return;

    half8 v;
    _Float16* dst;

    if (gid < E8) {
        int row = gid / 40, c8 = (gid - row * 40) * 8;
        #pragma unroll
        for (int j = 0; j < 8; ++j) {
            int c = c8 + j;
            float f = (c < 300) ? emb[(size_t)row * 300 + c] : 0.f;
            v[j] = (_Float16)(f > 0.f ? f : 0.f);
        }
        dst = embf + (size_t)gid * 8;
    } else if (gid < E8 + W18) {
        int i = gid - E8;
        int row = i / 200, c8 = (i - row * 200) * 8;
        #pragma unroll
        for (int j = 0; j < 8; ++j) {
            int c = c8 + j, w = c / 320, cc = c - w * 320;
            float f = (row < 300 && cc < 300) ? Wih1[(size_t)row * 1500 + w * 300 + cc] : 0.f;
            v[j] = (_Float16)f;
        }
        dst = Wf1 + (size_t)i * 8;
    } else if (gid < E8 + W18 + W28) {
        int i = gid - E8 - W18;
        int row = i / 40, c8 = (i - row * 40) * 8;
        #pragma unroll
        for (int j = 0; j < 8; ++j) {
            int c = c8 + j;
            float f = (row < 300 && c < 300) ? Wih2[(size_t)row * 300 + c] : 0.f;
            v[j] = (_Float16)f;
        }
        dst = Wf2 + (size_t)i * 8;
    } else if (gid < E8 + W18 + W28 + FF8) {
        int i = gid - E8 - W18 - W28;
        int row = i / 40, c8 = (i - row * 40) * 8;
        #pragma unroll
        for (int j = 0; j < 8; ++j) {
            int c = c8 + j;
            v[j] = (_Float16)((c < 300) ? fc1w[(size_t)row * 300 + c] : 0.f);
        }
        dst = F1 + (size_t)i * 8;
    } else {
        int i = gid - E8 - W18 - W28 - FF8;
        int row = i / 40, c8 = (i - row * 40) * 8;
        #pragma unroll
        for (int j = 0; j < 8; ++j) {
            int c = c8 + j;
            v[j] = (_Float16)((c < 300) ? fc2w[(size_t)row * 300 + c] : 0.f);
        }
        dst = F2 + (size_t)i * 8;
    }
    *(half8*)dst = v;
}

// ---------------------------------------------------------------------------
// GEMM1 (MFMA, fused embedding gather). grid (128,2), block 256.
// Writes U1T in fragment layout [t][G][b][j].
// ---------------------------------------------------------------------------
__global__ __launch_bounds__(256) void k_gemm1_mfma(
    const int* __restrict__ x, const _Float16* __restrict__ embf,
    const _Float16* __restrict__ Wf1, const float* __restrict__ b1,
    const float* __restrict__ b2, _Float16* __restrict__ U)
{
    const int wid  = threadIdx.x >> 6;
    const int lane = threadIdx.x & 63;
    const int m    = lane & 15;
    const int q    = lane >> 4;
    const int r0   = blockIdx.x * 128 + wid * 32;
    const int n0   = blockIdx.y * 160;
    const int t    = r0 >> 5;

    f32x4 acc[2][10];
    #pragma unroll
    for (int i = 0; i < 2; ++i)
        #pragma unroll
        for (int j = 0; j < 10; ++j)
            acc[i][j] = (f32x4){0.f, 0.f, 0.f, 0.f};

    const int rA = r0 + m, rB = r0 + 16 + m;
    const int xbA = ((rA & 31) * S_LEN + (rA >> 5)) * 5;
    const int xbB = ((rB & 31) * S_LEN + (rB >> 5)) * 5;

    for (int w = 0; w < 5; ++w) {
        const int idxA = x[xbA + w];
        const int idxB = x[xbB + w];
        const _Float16* ea = embf + (size_t)idxA * 320;
        const _Float16* eb = embf + (size_t)idxB * 320;
        const _Float16* wb = Wf1 + (size_t)w * 320;
        #pragma unroll
        for (int c = 0; c < 10; ++c) {
            const int k = c * 32 + q * 8;
            half8 a0 = *(const half8*)(ea + k);
            half8 a1 = *(const half8*)(eb + k);
            #pragma unroll
            for (int nt = 0; nt < 10; ++nt) {
                half8 bf = *(const half8*)(wb + (size_t)(n0 + nt * 16 + m) * 1600 + k);
                acc[0][nt] = __builtin_amdgcn_mfma_f32_16x16x32_f16(a0, bf, acc[0][nt], 0, 0, 0);
                acc[1][nt] = __builtin_amdgcn_mfma_f32_16x16x32_f16(a1, bf, acc[1][nt], 0, 0, 0);
            }
        }
    }

    #pragma unroll
    for (int nt = 0; nt < 10; ++nt) {
        const int n = n0 + nt * 16 + m;
        const int G = n >> 3, j = n & 7;
        const float bias = (n < 300) ? (b1[n] + b2[n]) : 0.f;
        #pragma unroll
        for (int mt = 0; mt < 2; ++mt) {
            #pragma unroll
            for (int reg = 0; reg < 4; ++reg) {
                const int b = mt * 16 + q * 4 + reg;
                U[(size_t)t * TSL + (G * 32 + b) * 8 + j] =
                    (_Float16)(acc[mt][nt][reg] + bias);
            }
        }
    }
}

// ---------------------------------------------------------------------------
// FC (MFMA): per-wave 32x128; H in fragment layout. grid (128,2): y=layer.
// ---------------------------------------------------------------------------
__global__ __launch_bounds__(256) void k_fc_mfma(
    const _Float16* __restrict__ H1, const _Float16* __restrict__ H2,
    const _Float16* __restrict__ F1, const _Float16* __restrict__ F2,
    const float* __restrict__ fb1, const float* __restrict__ fb2,
    float* __restrict__ out1, float* __restrict__ out2)
{
    const int layer = blockIdx.y;
    const _Float16* H = layer ? H2 : H1;
    const _Float16* F = layer ? F2 : F1;
    const float* bias = layer ? fb2 : fb1;
    float* out        = layer ? out2 : out1;

    const int wid  = threadIdx.x >> 6;
    const int lane = threadIdx.x & 63;
    const int m    = lane & 15;
    const int q    = lane >> 4;
    const int r0   = blockIdx.x * 128 + wid * 32;
    const int t    = r0 >> 5;

    f32x4 acc[2][8];
    #pragma unroll
    for (int i = 0; i < 2; ++i)
        #pragma unroll
        for (int j = 0; j < 8; ++j)
            acc[i][j] = (f32x4){0.f, 0.f, 0.f, 0.f};

    #pragma unroll
    for (int c = 0; c < 10; ++c) {
        const int k = c * 32 + q * 8;
        half8 a0 = *(const half8*)&H[(size_t)t * TSL + ((4 * c + q) * 32 + m) * 8];
        half8 a1 = *(const half8*)&H[(size_t)t * TSL + ((4 * c + q) * 32 + 16 + m) * 8];
        #pragma unroll
        for (int nt = 0; nt < 8; ++nt) {
            half8 bf = *(const half8*)(F + (size_t)(nt * 16 + m) * 320 + k);
            acc[0][nt] = __builtin_amdgcn_mfma_f32_16x16x32_f16(a0, bf, acc[0][nt], 0, 0, 0);
            acc[1][nt] = __builtin_amdgcn_mfma_f32_16x16x32_f16(a1, bf, acc[1][nt], 0, 0, 0);
        }
    }

    #pragma unroll
    for (int nt = 0; nt < 8; ++nt) {
        const int n = nt * 16 + m;
        const float bv = bias[n];
        #pragma unroll
        for (int mt = 0; mt < 2; ++mt) {
            #pragma unroll
            for (int reg = 0; reg < 4; ++reg) {
                const int r = r0 + mt * 16 + q * 4 + reg;
                const int oidx = ((r & 31) * S_LEN + (r >> 5)) * 128 + n;
                out[oidx] = acc[mt][nt][reg] + bv;
            }
        }
    }
}

// ---------------------------------------------------------------------------
// MFMA recurrence pipeline v2 (race-fixed). Grid 8 x 512:
//  blk 0,1 producer (layer1, 16 chains); blk 2-5 helper (Wih2·h1 chunk GEMM);
//  blk 6,7 consumer (layer2). All tensors in frag layout [t][G][b][j].
// U prefetch: crosses chunk boundary ONLY when there is no upstream
// dependency (producer); dependent path (consumer) re-loads upf after the
// flag wait each chunk.  <-- R8 bug fix
// LDS ring: 2 x 40 groups x GSTR(136) f16 = 21,760 B.
// ---------------------------------------------------------------------------
#define GSTR   136
#define BUFSTR (40 * GSTR)
#define LDS_BYTES (2 * BUFSTR * 2)

__device__ __forceinline__ void rec_core(
    const _Float16* __restrict__ Ut, const float* __restrict__ Whh,
    _Float16* __restrict__ Hf, int b0,
    unsigned int* relFlag, const unsigned int* waitA, const unsigned int* waitB,
    char* smem)
{
    const int tid  = threadIdx.x;
    const int lane = tid & 63;
    const int w    = tid >> 6;          // 0..7
    const int lm   = lane & 15;
    const int q    = lane >> 4;
    int ntile, tbase;
    if (w < 4) { ntile = 3; tbase = 3 * w; } else { ntile = 2; tbase = 12 + 2 * (w - 4); }

    const bool dep = (waitA != nullptr);   // consumer: U source produced live

    _Float16* ring = (_Float16*)smem;
    for (int i = tid; i < 2 * BUFSTR; i += 512) ring[i] = (_Float16)0.f;

    // W A-frags: wa[ti][kt] lane holds W[n=(tbase+ti)*16+lm][k=kt*32+q*8+j]
    half8 wa[3][10];
    for (int ti = 0; ti < 3; ++ti) {
        const int n = (tbase + ti) * 16 + lm;
        for (int kt = 0; kt < 10; ++kt) {
            half8 v;
            #pragma unroll
            for (int j = 0; j < 8; ++j) {
                const int k = kt * 32 + q * 8 + j;
                float f = (ti < ntile && n < 300 && k < 300) ? Whh[(size_t)n * 300 + k] : 0.f;
                v[j] = (_Float16)f;
            }
            wa[ti][kt] = v;
        }
    }
    __syncthreads();

    // per-ti element offset within a t-slice (global frag arrays)
    int toff[3];
    int loff[3];   // LDS ring offset
    #pragma unroll
    for (int ti = 0; ti < 3; ++ti) {
        const int T = tbase + ti;
        const int G = 2 * T + (q >> 1);
        toff[ti] = (G * 32 + b0 + lm) * 8 + 4 * (q & 1);
        loff[ti] = G * GSTR + lm * 8 + 4 * (q & 1);
    }

    hv4 upf[3], upn[3];
    #pragma unroll
    for (int ti = 0; ti < 3; ++ti) { upf[ti] = (hv4){0,0,0,0}; upn[ti] = (hv4){0,0,0,0}; }

    for (int c = 0; c < 32; ++c) {
        const int t0 = c * CHUNK;
        if (dep) {
            if (tid == 0) {
                while (__hip_atomic_load(waitA, __ATOMIC_ACQUIRE, __HIP_MEMORY_SCOPE_AGENT) < (unsigned)(t0 + CHUNK) ||
                       __hip_atomic_load(waitB, __ATOMIC_ACQUIRE, __HIP_MEMORY_SCOPE_AGENT) < (unsigned)(t0 + CHUNK))
                    __builtin_amdgcn_s_sleep(2);
            }
            __syncthreads();
        }
        // (re)load upf for this chunk's first step AFTER the wait (dep path);
        // producer only needs this once at c==0.
        if (c == 0 || dep) {
            #pragma unroll
            for (int ti = 0; ti < 3; ++ti)
                upf[ti] = *(const hv4*)&Ut[(size_t)t0 * TSL + toff[ti]];
        }

        for (int s = 0; s < CHUNK; ++s) {
            const int t = t0 + s;
            // prefetch next-step U (stays in flight behind MFMA). Dependent
            // path must NOT cross the chunk boundary (next chunk unwritten).
            const bool pf = dep ? (s < CHUNK - 1) : (t + 1 < S_LEN);
            if (pf) {
                #pragma unroll
                for (int ti = 0; ti < 3; ++ti)
                    upn[ti] = *(const hv4*)&Ut[(size_t)(t + 1) * TSL + toff[ti]];
            }
            const _Float16* rb = ring + ((t & 1) ^ 1) * BUFSTR;
            half8 hb[10];
            #pragma unroll
            for (int kt = 0; kt < 10; ++kt)
                hb[kt] = *(const half8*)(rb + (4 * kt + q) * GSTR + lm * 8);

            f32x4 aA[3], aB[3];
            #pragma unroll
            for (int ti = 0; ti < 3; ++ti) {
                aA[ti] = (f32x4){0.f, 0.f, 0.f, 0.f};
                aB[ti] = (f32x4){0.f, 0.f, 0.f, 0.f};
            }
            #pragma unroll
            for (int kt = 0; kt < 5; ++kt) {
                aA[0] = __builtin_amdgcn_mfma_f32_16x16x32_f16(wa[0][kt], hb[kt], aA[0], 0, 0, 0);
                aB[0] = __builtin_amdgcn_mfma_f32_16x16x32_f16(wa[0][kt + 5], hb[kt + 5], aB[0], 0, 0, 0);
                aA[1] = __builtin_amdgcn_mfma_f32_16x16x32_f16(wa[1][kt], hb[kt], aA[1], 0, 0, 0);
                aB[1] = __builtin_amdgcn_mfma_f32_16x16x32_f16(wa[1][kt + 5], hb[kt + 5], aB[1], 0, 0, 0);
                if (ntile > 2) {
                    aA[2] = __builtin_amdgcn_mfma_f32_16x16x32_f16(wa[2][kt], hb[kt], aA[2], 0, 0, 0);
                    aB[2] = __builtin_amdgcn_mfma_f32_16x16x32_f16(wa[2][kt + 5], hb[kt + 5], aB[2], 0, 0, 0);
                }
            }

            _Float16* wb = ring + (t & 1) * BUFSTR;
            #pragma unroll
            for (int ti = 0; ti < 3; ++ti) {
                if (ti < ntile) {
                    hv4 pk;
                    #pragma unroll
                    for (int r = 0; r < 4; ++r)
                        pk[r] = (_Float16)fast_tanh(aA[ti][r] + aB[ti][r] + (float)upf[ti][r]);
                    *(hv4*)(wb + loff[ti]) = pk;
                    *(hv4*)&Hf[(size_t)t * TSL + toff[ti]] = pk;
                }
            }
            lds_barrier();
            if (pf) { upf[0] = upn[0]; upf[1] = upn[1]; upf[2] = upn[2]; }
        }
        if (relFlag) {
            vm_drain();
            __syncthreads();
            if (tid == 0)
                __hip_atomic_store(relFlag, (unsigned)(t0 + CHUNK),
                                   __ATOMIC_RELEASE, __HIP_MEMORY_SCOPE_AGENT);
        }
    }
}

__global__ __launch_bounds__(512, 2) void k_rec_pipe(
    const _Float16* __restrict__ U1T, const float* __restrict__ Whh1,
    const float* __restrict__ Whh2, const _Float16* __restrict__ Wf2,
    const float* __restrict__ bih2, const float* __restrict__ bhh2,
    _Float16* __restrict__ H1f, _Float16* __restrict__ H2f,
    _Float16* __restrict__ U2T, unsigned int* __restrict__ flags)
{
    extern __shared__ char smem[];
    const int bx = blockIdx.x;

    if (bx < 2) {
        rec_core(U1T, Whh1, H1f, bx * 16, &flags[bx], nullptr, nullptr, smem);
    } else if (bx < 6) {
        // ------ helper: U2T = bias2 + Wih2 . h1  (per-chunk GEMM) ------
        const int idx = bx - 2;             // 0..3
        const int g   = idx >> 1;
        const int hh  = idx & 1;
        const int b0  = g * 16;
        const int tid = threadIdx.x;
        const int lane = tid & 63;
        const int w   = tid >> 6;
        const int lm  = lane & 15;
        const int q   = lane >> 4;
        const int ms  = w >> 1;
        const int th  = w & 1;
        const int mtb  = 10 * hh + ((5 * ms + 1) >> 1);   // {0,3,5,8}+10hh
        const int mcnt = 3 - (ms & 1);                    // {3,2,3,2}

        half8 af[3][10];
        float bs[12];
        int toff2[3];
        for (int ti = 0; ti < 3; ++ti) {
            const int nrow = (mtb + ti) * 16 + lm;
            for (int kt = 0; kt < 10; ++kt) {
                if (ti < mcnt)
                    af[ti][kt] = *(const half8*)&Wf2[(size_t)nrow * 320 + kt * 32 + q * 8];
                else {
                    half8 z;
                    #pragma unroll
                    for (int j = 0; j < 8; ++j) z[j] = (_Float16)0.f;
                    af[ti][kt] = z;
                }
            }
            #pragma unroll
            for (int r = 0; r < 4; ++r) {
                const int n = (mtb + ti) * 16 + q * 4 + r;
                bs[ti * 4 + r] = (ti < mcnt && n < 300) ? (bih2[n] + bhh2[n]) : 0.f;
            }
            toff2[ti] = ((2 * (mtb + ti) + (q >> 1)) * 32 + b0 + lm) * 8 + 4 * (q & 1);
        }

        for (int c = 0; c < 32; ++c) {
            const int t0 = c * CHUNK;
            if (tid == 0) {
                while (__hip_atomic_load(&flags[g], __ATOMIC_ACQUIRE,
                                         __HIP_MEMORY_SCOPE_AGENT) < (unsigned)(t0 + CHUNK))
                    __builtin_amdgcn_s_sleep(2);
            }
            __syncthreads();
            for (int tt = 0; tt < 8; ++tt) {
                const int t = t0 + th * 8 + tt;
                f32x4 a0 = {0.f,0.f,0.f,0.f}, a1 = {0.f,0.f,0.f,0.f}, a2 = {0.f,0.f,0.f,0.f};
                #pragma unroll
                for (int kt = 0; kt < 10; ++kt) {
                    half8 hb = *(const half8*)&H1f[(size_t)t * TSL + ((4 * kt + q) * 32 + b0 + lm) * 8];
                    a0 = __builtin_amdgcn_mfma_f32_16x16x32_f16(af[0][kt], hb, a0, 0, 0, 0);
                    a1 = __builtin_amdgcn_mfma_f32_16x16x32_f16(af[1][kt], hb, a1, 0, 0, 0);
                    if (mcnt > 2)
                        a2 = __builtin_amdgcn_mfma_f32_16x16x32_f16(af[2][kt], hb, a2, 0, 0, 0);
                }
                #pragma unroll
                for (int ti = 0; ti < 3; ++ti) {
                    if (ti < mcnt) {
                        const f32x4 aa = (ti == 0) ? a0 : ((ti == 1) ? a1 : a2);
                        hv4 pk;
                        #pragma unroll
                        for (int r = 0; r < 4; ++r)
                            pk[r] = (_Float16)(aa[r] + bs[ti * 4 + r]);
                        *(hv4*)&U2T[(size_t)t * TSL + toff2[ti]] = pk;
                    }
                }
            }
            vm_drain();
            __syncthreads();
            if (tid == 0)
                __hip_atomic_store(&flags[2 + idx], (unsigned)(t0 + CHUNK),
                                   __ATOMIC_RELEASE, __HIP_MEMORY_SCOPE_AGENT);
        }
    } else {
        const int g = bx - 6;
        rec_core(U2T, Whh2, H2f, g * 16, nullptr,
                 &flags[2 + 2 * g], &flags[2 + 2 * g + 1], smem);
    }
}

extern "C" void kernel_launch(void* const* d_in, const int* in_sizes, int n_in,
                              void* d_out, int out_size, void* d_ws, size_t ws_size,
                              hipStream_t stream) {
    const int*   x     = (const int*)d_in[0];
    const float* emb   = (const float*)d_in[1];
    const float* Wih1  = (const float*)d_in[2];
    const float* Whh1  = (const float*)d_in[3];
    const float* bih1  = (const float*)d_in[4];
    const float* bhh1  = (const float*)d_in[5];
    const float* Wih2  = (const float*)d_in[6];
    const float* Whh2  = (const float*)d_in[7];
    const float* bih2  = (const float*)d_in[8];
    const float* bhh2  = (const float*)d_in[9];
    const float* fc1w  = (const float*)d_in[10];
    const float* fc1b  = (const float*)d_in[11];
    const float* fc2w  = (const float*)d_in[12];
    const float* fc2b  = (const float*)d_in[13];

    float* out1 = (float*)d_out;
    float* out2 = out1 + (size_t)16384 * 128;

    char* w = (char*)d_ws;
    _Float16*     U1T   = (_Float16*)(w + 0);            // 10,485,760
    _Float16*     H1f   = (_Float16*)(w + 10485760);     // 10,485,760
    _Float16*     Wf2   = (_Float16*)(w + 20971520);     //    204,800
    _Float16*     F1    = (_Float16*)(w + 21176320);     //     81,920
    _Float16*     F2    = (_Float16*)(w + 21258240);     //     81,920
    unsigned int* flags = (unsigned int*)(w + 21340160); //        256
    _Float16*     EMBF  = (_Float16*)(w + 21340416);     // 20,480,000
    _Float16*     Wf1   = (_Float16*)(w + 41820416);     //  1,024,000
    // After gemm1, EMBF+Wf1 are dead -> reuse:
    _Float16*     H2f   = EMBF;                          // 10,485,760
    _Float16*     U2T   = (_Float16*)((char*)EMBF + 10485760); // 10,485,760

    const int prep_blocks = (PREP_TOTAL8 + 255) / 256;
    k_prep<<<prep_blocks, 256, 0, stream>>>(emb, Wih1, Wih2, fc1w, fc2w,
                                            EMBF, Wf1, Wf2, F1, F2, flags);

    dim3 g(128, 2);
    k_gemm1_mfma<<<g, 256, 0, stream>>>(x, EMBF, Wf1, bih1, bhh1, U1T);
    k_rec_pipe<<<8, 512, LDS_BYTES, stream>>>(U1T, Whh1, Whh2, Wf2, bih2, bhh2,
                                              H1f, H2f, U2T, flags);
    k_fc_mfma<<<g, 256, 0, stream>>>(H1f, H2f, F1, F2, fc1b, fc2b, out1, out2);
}